// Round 5
// baseline (127.388 us; speedup 1.0000x reference)
//
#include <hip/hip_runtime.h>
#include <cstdint>
#include <cstddef>

// Sparse submanifold 3x3x3 conv, C_in=C_out=64, fp32. SHAPE=(256,256,256), BS=2
// -> packed key = (b<<24)|(x<<16)|(y<<8)|z (25 bits used).
//
// center tap (k=13): dense 200K x 64 @ 64 x 64 GEMM via bf16 MFMA
// (16x16x32), W13 pre-packed into fragment order. Non-center taps (~31K
// hits -> ~62K pairs): probe compacts (site,k,nbi) bucketed BY TAP k into 27
// regions; conv_pairs assigns 48 blocks per region (W[k] L1-resident).
//
// R1: 13 offsets (mutual symmetry, emit both directions), batched MLP probe.
// R2: FAILED — 12.5K blocks x same-address reservation atomic ~110us chain.
// R3: conv_pairs region-loop collapsed parallelism (occ 7%) -> 114us.
// R4: per-k bucketing + static region/block in conv_pairs; probe 43.7us top.
// R5(this): probe is pinned ~44us by per-CU divergent-gather pipe throughput,
//     NOT TLP (R1 12w=45.6 vs R4 24w=43.7) — CU is idle 89%. So: (a) FUSE
//     center GEMM into probe kernel, 1:1 block interleave, so center's
//     MFMA+streaming runs in probe's stall cycles (was 17us serial);
//     (b) pack key|val<<32 into one u64 table entry (same 4MB footprint,
//     one load per probe step instead of keys+vals dependent pair).

typedef __attribute__((ext_vector_type(8))) short bf16x8;
typedef __attribute__((ext_vector_type(4))) float f32x4;

static constexpr unsigned long long EMPTY64 = ~0ull;
static constexpr int LCAP = 512;      // LDS-staged pairs per block (expected ~40)
static constexpr unsigned NREGION = 27;  // pair regions, indexed by tap k
static constexpr unsigned CPAD = 16;     // counter padding (uints): 64B apart
static constexpr int PB = 48;         // conv_pairs blocks per region

__device__ __forceinline__ unsigned hash_mix(unsigned key) {
    unsigned h = key * 0x9E3779B1u;
    h ^= h >> 15;
    return h;
}

__device__ __forceinline__ unsigned short f2bf(float x) {  // RNE fp32->bf16
    unsigned u = __builtin_bit_cast(unsigned, x);
    return (unsigned short)((u + 0x7FFFu + ((u >> 16) & 1u)) >> 16);
}

// init: clear hash table (u64 entries), zero padded region counters, build
// W13 bf16 fragment table. wfrag entry e = (ks*4 + nt)*64 + lane, elem j =
// bf16(W13[ks*32+(lane>>4)*8+j][nt*16+(lane&15)]).
__global__ void init_table_kernel(unsigned long long* __restrict__ table,
                                  int nslots, unsigned* __restrict__ cnts,
                                  const float* __restrict__ weight,
                                  unsigned short* __restrict__ wfrag) {
    int i = blockIdx.x * blockDim.x + threadIdx.x;
    if (i < nslots) table[i] = EMPTY64;
    if (i < 512) {
        cnts[i] = 0u;   // covers NREGION*CPAD = 432 padded counters
        const int lane = i & 63, nt = (i >> 6) & 3, ks = i >> 8;
        const float* __restrict__ w13 = weight + 13 * 4096;
        #pragma unroll
        for (int j = 0; j < 8; ++j) {
            const int k = ks * 32 + (lane >> 4) * 8 + j;
            const int n = nt * 16 + (lane & 15);
            wfrag[(size_t)i * 8 + j] = f2bf(w13[k * 64 + n]);
        }
    }
}

__global__ void insert_kernel(const int4* __restrict__ coords, int n,
                              unsigned long long* __restrict__ table,
                              unsigned mask) {
    int i = blockIdx.x * blockDim.x + threadIdx.x;
    if (i >= n) return;
    const int4 c = coords[i];   // (b, x, y, z)
    const unsigned key = ((unsigned)c.x << 24) | ((unsigned)c.y << 16) |
                         ((unsigned)c.z << 8) | (unsigned)c.w;
    const unsigned long long entry =
        (unsigned long long)key | ((unsigned long long)(unsigned)i << 32);
    unsigned s = hash_mix(key) & mask;
    while (atomicCAS((unsigned long long*)&table[s], EMPTY64, entry) !=
           EMPTY64)
        s = (s + 1) & mask;   // coords unique -> no duplicate keys
}

// Fused probe + center-GEMM kernel. Blocks interleave 1:1 by parity while
// probe blocks last (even bid -> probe bid/2, odd -> center bid/2; tail ->
// center bid-nprobe), so each CU co-schedules latency-stalled probe waves
// with MFMA/streaming center waves.
//
// Probe: two threads per site (t=0: k=0..6, t=1: k=7..12; each hit also
// emits mirror (nbi,26-k,site)). Phase 1 issues all first-round table loads
// independently (MLP); phase 2 resolves (u64 entry = key|nbi<<32, no second
// load). Hits staged in LDS, flushed bucketed by tap k.
//
// Center: out = bias + feats @ W13 via mfma_f32_16x16x32_bf16, one wave per
// 16 sites. A: row=lane&15, kdim=(lane>>4)*8+j (+ks*32). B pre-packed in
// wfrag. C/D: col=lane&15, row=(lane>>4)*4+reg.
__global__ __launch_bounds__(256) void probe_center_fused(
    const int4* __restrict__ coords, int n,
    const unsigned long long* __restrict__ table, unsigned mask,
    unsigned* __restrict__ cnts, uint2* __restrict__ pairs, unsigned rcap,
    const float* __restrict__ feats, const unsigned short* __restrict__ wfrag,
    const float* __restrict__ bias, float* __restrict__ out, int nprobe)
{
    __shared__ unsigned lcnt;
    __shared__ unsigned lk[32], lkb[32], lkp[32];
    __shared__ uint2 lbuf[LCAP];

    const int bid = blockIdx.x;
    int pb = -1, cb = -1;
    if (bid < 2 * nprobe) {
        if ((bid & 1) == 0) pb = bid >> 1; else cb = bid >> 1;
    } else {
        cb = bid - nprobe;
    }

    if (pb >= 0) {
        // ---------------- probe path ----------------
        if (threadIdx.x == 0) lcnt = 0u;
        if (threadIdx.x < 32) lk[threadIdx.x] = 0u;
        __syncthreads();

        const int t = threadIdx.x & 1;
        const int site = (pb * 256 + threadIdx.x) >> 1;
        if (site < n) {
            const int4 c = coords[site];
            const int k0 = t * 7;          // t=0: k=0..6, t=1: k=7..12
            const int nk = 7 - t;          // 7 or 6 active offsets
            unsigned long long kv[7];
            unsigned vmask = 0u;

            // phase 1: all first-round loads in flight (no inter-iter deps)
            #pragma unroll
            for (int j = 0; j < 7; ++j) {
                const int k = k0 + j;
                const int dx = k / 9 - 1, dy = (k / 3) % 3 - 1, dz = k % 3 - 1;
                const int nx = c.y + dx, ny = c.z + dy, nz = c.w + dz;
                const bool inb = (j < nk) && (((nx | ny | nz) & ~255) == 0);
                vmask |= inb ? (1u << j) : 0u;
                const unsigned key = ((unsigned)c.x << 24) |
                                     ((unsigned)nx << 16) |
                                     ((unsigned)ny << 8) | (unsigned)nz;
                kv[j] = inb ? table[hash_mix(key) & mask] : EMPTY64;
            }

            // phase 2: resolve (recompute slot; entry carries key AND nbi)
            #pragma unroll
            for (int j = 0; j < 7; ++j) {
                if (!((vmask >> j) & 1u)) continue;
                const int k = k0 + j;
                const int dx = k / 9 - 1, dy = (k / 3) % 3 - 1, dz = k % 3 - 1;
                const unsigned key = ((unsigned)c.x << 24) |
                                     ((unsigned)(c.y + dx) << 16) |
                                     ((unsigned)(c.z + dy) << 8) |
                                     (unsigned)(c.w + dz);
                unsigned s = hash_mix(key) & mask;
                unsigned long long e = kv[j];
                while (e != EMPTY64) {
                    if ((unsigned)e == key) {
                        const unsigned nbi = (unsigned)(e >> 32);
                        const uint2 p0 = make_uint2(
                            (unsigned)site | ((unsigned)k << 18), nbi);
                        const uint2 p1 = make_uint2(
                            nbi | ((unsigned)(26 - k) << 18), (unsigned)site);
                        const unsigned li = atomicAdd(&lcnt, 2u);
                        if (li + 1 < (unsigned)LCAP) { // li even, LCAP even
                            lbuf[li] = p0;
                            lbuf[li + 1] = p1;
                        } else {                        // statistically ~never
                            const unsigned g0 =
                                atomicAdd(&cnts[k * CPAD], 1u);
                            if (g0 < rcap) pairs[(size_t)k * rcap + g0] = p0;
                            const unsigned g1 =
                                atomicAdd(&cnts[(26 - k) * CPAD], 1u);
                            if (g1 < rcap)
                                pairs[(size_t)(26 - k) * rcap + g1] = p1;
                        }
                        break;
                    }
                    s = (s + 1) & mask;
                    e = table[s];
                }
            }
        }

        __syncthreads();
        const unsigned nloc = lcnt < (unsigned)LCAP ? lcnt : (unsigned)LCAP;
        // per-k histogram of staged pairs
        for (unsigned i = threadIdx.x; i < nloc; i += blockDim.x)
            atomicAdd(&lk[lbuf[i].x >> 18], 1u);
        __syncthreads();
        // one padded global reservation per nonempty k
        if (threadIdx.x < NREGION) {
            const unsigned c = lk[threadIdx.x];
            lkb[threadIdx.x] =
                c ? atomicAdd(&cnts[threadIdx.x * CPAD], c) : 0u;
            lkp[threadIdx.x] = 0u;
        }
        __syncthreads();
        // scatter into per-k regions
        for (unsigned i = threadIdx.x; i < nloc; i += blockDim.x) {
            const uint2 e = lbuf[i];
            const unsigned kk = e.x >> 18;
            const unsigned pos = atomicAdd(&lkp[kk], 1u);
            const unsigned idx = lkb[kk] + pos;
            if (idx < rcap) pairs[(size_t)kk * rcap + idx] = e;
        }
    } else {
        // ---------------- center-GEMM path ----------------
        const int lane = threadIdx.x & 63;
        const int wid = cb * 4 + (threadIdx.x >> 6);
        const int s0 = wid * 16;
        if (s0 >= n) return;

        // B fragments: 2 ksteps x 4 ntiles, 16B per lane each
        bf16x8 bfrag[2][4];
        #pragma unroll
        for (int ks = 0; ks < 2; ++ks)
            #pragma unroll
            for (int nt = 0; nt < 4; ++nt)
                bfrag[ks][nt] = *reinterpret_cast<const bf16x8*>(
                    wfrag + ((size_t)((ks * 4 + nt) * 64 + lane)) * 8);

        const int arow = s0 + (lane & 15);
        const bool vrow = arow < n;
        const float* __restrict__ fbase =
            feats + (size_t)(vrow ? arow : 0) * 64 + (lane >> 4) * 8;

        f32x4 acc[4] = {{0.f, 0.f, 0.f, 0.f}, {0.f, 0.f, 0.f, 0.f},
                        {0.f, 0.f, 0.f, 0.f}, {0.f, 0.f, 0.f, 0.f}};

        #pragma unroll
        for (int ks = 0; ks < 2; ++ks) {
            const f32x4 flo = *reinterpret_cast<const f32x4*>(fbase + ks * 32);
            const f32x4 fhi =
                *reinterpret_cast<const f32x4*>(fbase + ks * 32 + 4);
            bf16x8 afrag;
            afrag[0] = (short)f2bf(flo.x); afrag[1] = (short)f2bf(flo.y);
            afrag[2] = (short)f2bf(flo.z); afrag[3] = (short)f2bf(flo.w);
            afrag[4] = (short)f2bf(fhi.x); afrag[5] = (short)f2bf(fhi.y);
            afrag[6] = (short)f2bf(fhi.z); afrag[7] = (short)f2bf(fhi.w);
            #pragma unroll
            for (int nt = 0; nt < 4; ++nt)
                acc[nt] = __builtin_amdgcn_mfma_f32_16x16x32_bf16(
                    afrag, bfrag[ks][nt], acc[nt], 0, 0, 0);
        }

        const int crow0 = s0 + (lane >> 4) * 4;
        const int col = lane & 15;
        #pragma unroll
        for (int nt = 0; nt < 4; ++nt) {
            const float bv = bias[nt * 16 + col];
            #pragma unroll
            for (int r = 0; r < 4; ++r) {
                const int sr = crow0 + r;
                if (sr < n)
                    out[(size_t)sr * 64 + nt * 16 + col] = acc[nt][r] + bv;
            }
        }
    }
}

// 48 blocks per tap region; one wave per pair (grid-stride within region).
// All waves of a block stream the same 16KB W[k] -> L1-resident after the
// first pair. fp32 FMA + atomics (bit-identical math to R0's pairs path).
__global__ __launch_bounds__(256) void conv_pairs_kernel(
    const float* __restrict__ feats, const float* __restrict__ weight,
    const uint2* __restrict__ pairs, const unsigned* __restrict__ cnts,
    unsigned rcap, float* __restrict__ out)
{
    const int lane = threadIdx.x & 63;
    int r = blockIdx.x / PB;
    r += (r >= 13);                     // taps 0..12,14..26
    unsigned cnt = cnts[r * CPAD];
    if (cnt > rcap) cnt = rcap;
    if (cnt == 0) return;
    const uint2* __restrict__ rp = pairs + (size_t)r * rcap;
    const float* __restrict__ wk = weight + (size_t)r * 4096;
    const unsigned wloc = (blockIdx.x % PB) * 4 + (threadIdx.x >> 6);
    for (unsigned p = wloc; p < cnt; p += (unsigned)(PB * 4)) {
        const uint2 pr = rp[p];
        const unsigned site = pr.x & 0x3FFFFu;
        const unsigned nbi = pr.y;
        const float4* __restrict__ fr =
            reinterpret_cast<const float4*>(feats + (size_t)nbi * 64);
        float a0 = 0.f, a1 = 0.f, a2 = 0.f, a3 = 0.f;
        #pragma unroll
        for (int q = 0; q < 16; ++q) {
            const float4 f = fr[q];
            a0 = fmaf(f.x, wk[(4 * q + 0) * 64 + lane], a0);
            a1 = fmaf(f.y, wk[(4 * q + 1) * 64 + lane], a1);
            a2 = fmaf(f.z, wk[(4 * q + 2) * 64 + lane], a2);
            a3 = fmaf(f.w, wk[(4 * q + 3) * 64 + lane], a3);
        }
        atomicAdd(&out[(size_t)site * 64 + lane], (a0 + a1) + (a2 + a3));
    }
}

extern "C" void kernel_launch(void* const* d_in, const int* in_sizes, int n_in,
                              void* d_out, int out_size, void* d_ws, size_t ws_size,
                              hipStream_t stream) {
    const float* feats  = (const float*)d_in[0];   // (N, 64)
    const int4*  coords = (const int4*)d_in[1];    // (N, 4)
    const float* weight = (const float*)d_in[2];   // (27, 64, 64)
    const float* bias   = (const float*)d_in[3];   // (64,)
    float* out = (float*)d_out;

    const int n = in_sizes[1] / 4;

    // ws layout: table (nslots u64) | cnts (2KB = 27 padded counters)
    //            | wfrag (8KB) | pairs (27 regions x rcap)
    const bool big = ws_size >= ((size_t)16 << 20);
    const int nslots = big ? (1 << 19) : (1 << 18);
    const unsigned mask = (unsigned)(nslots - 1);
    unsigned long long* table = (unsigned long long*)d_ws;
    unsigned* cnts = (unsigned*)(table + nslots);
    unsigned short* wfrag = (unsigned short*)((char*)cnts + 2048);
    uint2* pairs = (uint2*)((char*)wfrag + 8192);
    const size_t used = (size_t)nslots * 8 + 2048 + 8192;
    size_t cap_sz = (ws_size > used) ? (ws_size - used) / sizeof(uint2) : 0;
    if (cap_sz > (size_t)(4 << 20)) cap_sz = (size_t)(4 << 20);
    const unsigned rcap = (unsigned)(cap_sz / NREGION);

    {
        int blocks = (nslots + 255) / 256;
        init_table_kernel<<<blocks, 256, 0, stream>>>(table, nslots, cnts,
                                                      weight, wfrag);
    }
    {
        int blocks = (n + 255) / 256;
        insert_kernel<<<blocks, 256, 0, stream>>>(coords, n, table, mask);
    }
    {
        const int nprobe = (n + 127) / 128;        // 128 sites/block, 2 thr/site
        const int ncwaves = (n + 15) / 16;
        const int ncenter = (ncwaves + 3) / 4;     // 4 waves/block
        // 1:1 parity interleave while probe lasts; 2*ceil(n/128) >= ceil(n/64)
        // guarantees all center ids are covered by the mapping.
        const int total = nprobe + ncenter;
        probe_center_fused<<<total, 256, 0, stream>>>(
            coords, n, table, mask, cnts, pairs, rcap,
            feats, wfrag, bias, out, nprobe);
    }
    {
        conv_pairs_kernel<<<26 * PB, 256, 0, stream>>>(feats, weight, pairs,
                                                       cnts, rcap, out);
    }
}

// Round 6
// 99.401 us; speedup vs baseline: 1.2816x; 1.2816x over previous
//
#include <hip/hip_runtime.h>
#include <cstdint>
#include <cstddef>

// Sparse submanifold 3x3x3 conv, C_in=C_out=64, fp32. SHAPE=(256,256,256), BS=2
// -> packed key = (b<<24)|(x<<16)|(y<<8)|z  == linear voxel id (25 bits).
//
// center tap (k=13): dense 200K x 64 @ 64 x 64 GEMM via bf16 MFMA
// (16x16x32), W13 pre-packed into fragment order. Non-center taps: probe
// tests a 4.2MB dense occupancy BITMAP (bit index == key) for the 13
// symmetric offsets (5 (dx,dy) row-groups x z-triple bits), and only on a
// set bit does a hash lookup (u64 key|idx entry) to fetch the neighbor
// index; pairs bucketed by tap k into 27 regions; conv_pairs assigns 48
// blocks per region (W[k] L1-resident), fp32 FMA + atomics.
//
// R1: 13 offsets (mutual symmetry), batched MLP probe.
// R2: FAILED — 12.5K same-address reservation atomics = serialized chain.
// R3: conv_pairs region-loop collapsed parallelism (occ 7%).
// R4: per-k bucketing + static region/block conv_pairs; probe 43.7us top.
// R5: FAILED — probe+center fusion 80us ≈ (3.4M+6.4M req)/256CU x ~8cyc:
//     BOTH paths are per-CU vmem-pipe bound; memory work doesn't overlap
//     memory work. Model: divergent line-fill ~6-8 cyc/CU (R0/R1/R4 agree).
// R6(this): fusion reverted; probe existence test moved to the dense
//     bitmap: ~5.3 aligned u32 loads/site (q&31==z&31 so word-edge case is
//     thread-uniform, edge load exec-masked ~6% of lanes) vs ~17 divergent
//     hash lines/site. Hash walk only for ~16K hit sites. Requests 3.4M->1.1M.

typedef __attribute__((ext_vector_type(8))) short bf16x8;
typedef __attribute__((ext_vector_type(4))) float f32x4;

static constexpr unsigned long long EMPTY64 = ~0ull;
static constexpr int LCAP = 512;      // LDS-staged pairs per block (expected ~80)
static constexpr unsigned NREGION = 27;  // pair regions, indexed by tap k
static constexpr unsigned CPAD = 16;     // counter padding (uints): 64B apart
static constexpr int PB = 48;         // conv_pairs blocks per region
static constexpr int NBWORDS = (2 << 24) >> 5;   // bitmap u32 words (BS=2): 1M

__device__ __forceinline__ unsigned hash_mix(unsigned key) {
    unsigned h = key * 0x9E3779B1u;
    h ^= h >> 15;
    return h;
}

__device__ __forceinline__ unsigned short f2bf(float x) {  // RNE fp32->bf16
    unsigned u = __builtin_bit_cast(unsigned, x);
    return (unsigned short)((u + 0x7FFFu + ((u >> 16) & 1u)) >> 16);
}

// init: clear hash table (u64), clear bitmap, zero padded region counters,
// build W13 bf16 fragment table. wfrag entry e = (ks*4 + nt)*64 + lane,
// elem j = bf16(W13[ks*32+(lane>>4)*8+j][nt*16+(lane&15)]).
__global__ void init_table_kernel(unsigned long long* __restrict__ table,
                                  int nslots, unsigned* __restrict__ bitmap,
                                  int nbwords, unsigned* __restrict__ cnts,
                                  const float* __restrict__ weight,
                                  unsigned short* __restrict__ wfrag) {
    int i = blockIdx.x * blockDim.x + threadIdx.x;
    if (i < nslots) table[i] = EMPTY64;
    if (i < nbwords) bitmap[i] = 0u;
    if (i < 512) {
        cnts[i] = 0u;   // covers NREGION*CPAD = 432 padded counters
        const int lane = i & 63, nt = (i >> 6) & 3, ks = i >> 8;
        const float* __restrict__ w13 = weight + 13 * 4096;
        #pragma unroll
        for (int j = 0; j < 8; ++j) {
            const int k = ks * 32 + (lane >> 4) * 8 + j;
            const int n = nt * 16 + (lane & 15);
            wfrag[(size_t)i * 8 + j] = f2bf(w13[k * 64 + n]);
        }
    }
}

// insert into hash table (u64 key|idx entry) AND set occupancy bit.
__global__ void insert_kernel(const int4* __restrict__ coords, int n,
                              unsigned long long* __restrict__ table,
                              unsigned mask, unsigned* __restrict__ bitmap) {
    int i = blockIdx.x * blockDim.x + threadIdx.x;
    if (i >= n) return;
    const int4 c = coords[i];   // (b, x, y, z)
    const unsigned key = ((unsigned)c.x << 24) | ((unsigned)c.y << 16) |
                         ((unsigned)c.z << 8) | (unsigned)c.w;
    atomicOr(&bitmap[key >> 5], 1u << (key & 31));
    const unsigned long long entry =
        (unsigned long long)key | ((unsigned long long)(unsigned)i << 32);
    unsigned s = hash_mix(key) & mask;
    while (atomicCAS((unsigned long long*)&table[s], EMPTY64, entry) !=
           EMPTY64)
        s = (s + 1) & mask;   // coords unique -> no duplicate keys
}

// One thread per site. Existence via bitmap: 5 (dx,dy) groups covering the
// 13 symmetric offsets k<13 (k = 3*g + d, d = dz+1; group 4 only d=0);
// each group reads bits (q-1,q,q+1) of its row word (aligned u32; word-edge
// r=z&31 in {0,31} is thread-uniform, extra word exec-masked). Hits (rare)
// resolve the neighbor index via the u64 hash table and emit (site,k,nbi)
// AND mirror (nbi,26-k,site) into LDS; flush bucketed by tap k.
__global__ __launch_bounds__(512) void probe_pairs_kernel(
    const int4* __restrict__ coords, int n,
    const unsigned long long* __restrict__ table, unsigned mask,
    const unsigned* __restrict__ bitmap,
    unsigned* __restrict__ cnts, uint2* __restrict__ pairs, unsigned rcap)
{
    __shared__ unsigned lcnt;
    __shared__ unsigned lk[32], lkb[32], lkp[32];
    __shared__ uint2 lbuf[LCAP];
    if (threadIdx.x == 0) lcnt = 0u;
    if (threadIdx.x < 32) lk[threadIdx.x] = 0u;
    __syncthreads();

    const int site = blockIdx.x * blockDim.x + threadIdx.x;
    if (site < n) {
        const int4 c = coords[site];
        const int z = c.w;
        const int r = z & 31;           // bit offset within word, same all groups

        // phase 1: all bitmap row-words in flight (no inter-iter deps)
        unsigned lo[5], ex[5];
        #pragma unroll
        for (int g = 0; g < 5; ++g) {
            const int dx = (g < 3) ? -1 : 0;
            const int dy = (g < 3) ? (g - 1) : (g - 4);
            const int nx = c.y + dx, ny = c.z + dy;
            const bool rv = (((nx | ny) & ~255) == 0);
            const int q = ((((c.x << 8) | (nx & 255)) << 8) | (ny & 255)) << 8 | z;
            const int wq = q >> 5;
            lo[g] = rv ? bitmap[wq] : 0u;
            ex[g] = (rv && r == 31) ? bitmap[wq + 1]
                  : ((rv && r == 0 && wq > 0) ? bitmap[wq - 1] : 0u);
        }

        // phase 2: assemble hit mask (bit 3*g+d <-> offset (dx,dy,dz=d-1))
        const unsigned zmask =
            ((z == 0) ? ~1u : ~0u) & ((z == 255) ? ~4u : ~0u);
        unsigned hitm = 0u;
        #pragma unroll
        for (int g = 0; g < 5; ++g) {
            unsigned tri;
            if (r == 0)        tri = ((lo[g] & 3u) << 1) | (ex[g] >> 31);
            else if (r == 31)  tri = ((lo[g] >> 30) & 3u) | ((ex[g] & 1u) << 2);
            else               tri = (lo[g] >> (r - 1)) & 7u;
            tri &= zmask;
            if (g == 4) tri &= 1u;      // center group: only dz=-1 (k=12)
            hitm |= tri << (3 * g);
        }

        // phase 3: resolve hits via hash table (present by construction)
        while (hitm) {
            const int b = __ffs(hitm) - 1;
            hitm &= hitm - 1;
            const int g = b / 3, d = b % 3;         // k = 3g+d, dz = d-1
            const int dx = (g < 3) ? -1 : 0;
            const int dy = (g < 3) ? (g - 1) : (g - 4);
            const int k = 3 * g + d;
            const unsigned key = ((unsigned)c.x << 24) |
                                 ((unsigned)(c.y + dx) << 16) |
                                 ((unsigned)(c.z + dy) << 8) |
                                 (unsigned)(z + d - 1);
            unsigned s = hash_mix(key) & mask;
            unsigned long long e = table[s];
            while (e != EMPTY64 && (unsigned)e != key) {
                s = (s + 1) & mask;
                e = table[s];
            }
            if (e == EMPTY64) continue;             // defensive (can't happen)
            const unsigned nbi = (unsigned)(e >> 32);
            const uint2 p0 = make_uint2((unsigned)site | ((unsigned)k << 18),
                                        nbi);
            const uint2 p1 = make_uint2(nbi | ((unsigned)(26 - k) << 18),
                                        (unsigned)site);
            const unsigned li = atomicAdd(&lcnt, 2u);
            if (li + 1 < (unsigned)LCAP) {          // li even, LCAP even
                lbuf[li] = p0;
                lbuf[li + 1] = p1;
            } else {                                 // statistically ~never
                const unsigned g0 = atomicAdd(&cnts[k * CPAD], 1u);
                if (g0 < rcap) pairs[(size_t)k * rcap + g0] = p0;
                const unsigned g1 = atomicAdd(&cnts[(26 - k) * CPAD], 1u);
                if (g1 < rcap) pairs[(size_t)(26 - k) * rcap + g1] = p1;
            }
        }
    }

    __syncthreads();
    const unsigned nloc = lcnt < (unsigned)LCAP ? lcnt : (unsigned)LCAP;
    // per-k histogram of staged pairs
    for (unsigned i = threadIdx.x; i < nloc; i += blockDim.x)
        atomicAdd(&lk[lbuf[i].x >> 18], 1u);
    __syncthreads();
    // one padded global reservation per nonempty k
    if (threadIdx.x < NREGION) {
        const unsigned c = lk[threadIdx.x];
        lkb[threadIdx.x] = c ? atomicAdd(&cnts[threadIdx.x * CPAD], c) : 0u;
        lkp[threadIdx.x] = 0u;
    }
    __syncthreads();
    // scatter into per-k regions
    for (unsigned i = threadIdx.x; i < nloc; i += blockDim.x) {
        const uint2 e = lbuf[i];
        const unsigned kk = e.x >> 18;
        const unsigned pos = atomicAdd(&lkp[kk], 1u);
        const unsigned idx = lkb[kk] + pos;
        if (idx < rcap) pairs[(size_t)kk * rcap + idx] = e;
    }
}

// Dense center GEMM via MFMA: out = bias + feats @ W13.
// One wave per 16 sites x 64 oc. A: row=lane&15, k=(lane>>4)*8+j (+ks*32).
// B pre-packed in wfrag. C/D: col=lane&15, row=(lane>>4)*4+reg.
__global__ __launch_bounds__(256) void conv_center_mfma(
    const float* __restrict__ feats, const unsigned short* __restrict__ wfrag,
    const float* __restrict__ bias, float* __restrict__ out, int n)
{
    const int lane = threadIdx.x & 63;
    const int wid = blockIdx.x * (blockDim.x >> 6) + (threadIdx.x >> 6);
    const int s0 = wid * 16;
    if (s0 >= n) return;

    // B fragments: 2 ksteps x 4 ntiles, 16B per lane each
    bf16x8 bfrag[2][4];
    #pragma unroll
    for (int ks = 0; ks < 2; ++ks)
        #pragma unroll
        for (int nt = 0; nt < 4; ++nt)
            bfrag[ks][nt] = *reinterpret_cast<const bf16x8*>(
                wfrag + ((size_t)((ks * 4 + nt) * 64 + lane)) * 8);

    const int arow = s0 + (lane & 15);
    const bool vrow = arow < n;
    const float* __restrict__ fbase =
        feats + (size_t)(vrow ? arow : 0) * 64 + (lane >> 4) * 8;

    f32x4 acc[4] = {{0.f, 0.f, 0.f, 0.f}, {0.f, 0.f, 0.f, 0.f},
                    {0.f, 0.f, 0.f, 0.f}, {0.f, 0.f, 0.f, 0.f}};

    #pragma unroll
    for (int ks = 0; ks < 2; ++ks) {
        const f32x4 flo = *reinterpret_cast<const f32x4*>(fbase + ks * 32);
        const f32x4 fhi = *reinterpret_cast<const f32x4*>(fbase + ks * 32 + 4);
        bf16x8 afrag;
        afrag[0] = (short)f2bf(flo.x); afrag[1] = (short)f2bf(flo.y);
        afrag[2] = (short)f2bf(flo.z); afrag[3] = (short)f2bf(flo.w);
        afrag[4] = (short)f2bf(fhi.x); afrag[5] = (short)f2bf(fhi.y);
        afrag[6] = (short)f2bf(fhi.z); afrag[7] = (short)f2bf(fhi.w);
        #pragma unroll
        for (int nt = 0; nt < 4; ++nt)
            acc[nt] = __builtin_amdgcn_mfma_f32_16x16x32_bf16(
                afrag, bfrag[ks][nt], acc[nt], 0, 0, 0);
    }

    const int crow0 = s0 + (lane >> 4) * 4;
    const int col = lane & 15;
    #pragma unroll
    for (int nt = 0; nt < 4; ++nt) {
        const float bv = bias[nt * 16 + col];
        #pragma unroll
        for (int r = 0; r < 4; ++r) {
            const int sr = crow0 + r;
            if (sr < n)
                out[(size_t)sr * 64 + nt * 16 + col] = acc[nt][r] + bv;
        }
    }
}

// 48 blocks per tap region; one wave per pair (grid-stride within region).
// All waves of a block stream the same 16KB W[k] -> L1-resident after the
// first pair. fp32 FMA + atomics (bit-identical math to R0's pairs path).
__global__ __launch_bounds__(256) void conv_pairs_kernel(
    const float* __restrict__ feats, const float* __restrict__ weight,
    const uint2* __restrict__ pairs, const unsigned* __restrict__ cnts,
    unsigned rcap, float* __restrict__ out)
{
    const int lane = threadIdx.x & 63;
    int r = blockIdx.x / PB;
    r += (r >= 13);                     // taps 0..12,14..26
    unsigned cnt = cnts[r * CPAD];
    if (cnt > rcap) cnt = rcap;
    if (cnt == 0) return;
    const uint2* __restrict__ rp = pairs + (size_t)r * rcap;
    const float* __restrict__ wk = weight + (size_t)r * 4096;
    const unsigned wloc = (blockIdx.x % PB) * 4 + (threadIdx.x >> 6);
    for (unsigned p = wloc; p < cnt; p += (unsigned)(PB * 4)) {
        const uint2 pr = rp[p];
        const unsigned site = pr.x & 0x3FFFFu;
        const unsigned nbi = pr.y;
        const float4* __restrict__ fr =
            reinterpret_cast<const float4*>(feats + (size_t)nbi * 64);
        float a0 = 0.f, a1 = 0.f, a2 = 0.f, a3 = 0.f;
        #pragma unroll
        for (int q = 0; q < 16; ++q) {
            const float4 f = fr[q];
            a0 = fmaf(f.x, wk[(4 * q + 0) * 64 + lane], a0);
            a1 = fmaf(f.y, wk[(4 * q + 1) * 64 + lane], a1);
            a2 = fmaf(f.z, wk[(4 * q + 2) * 64 + lane], a2);
            a3 = fmaf(f.w, wk[(4 * q + 3) * 64 + lane], a3);
        }
        atomicAdd(&out[(size_t)site * 64 + lane], (a0 + a1) + (a2 + a3));
    }
}

extern "C" void kernel_launch(void* const* d_in, const int* in_sizes, int n_in,
                              void* d_out, int out_size, void* d_ws, size_t ws_size,
                              hipStream_t stream) {
    const float* feats  = (const float*)d_in[0];   // (N, 64)
    const int4*  coords = (const int4*)d_in[1];    // (N, 4)
    const float* weight = (const float*)d_in[2];   // (27, 64, 64)
    const float* bias   = (const float*)d_in[3];   // (64,)
    float* out = (float*)d_out;

    const int n = in_sizes[1] / 4;

    // ws layout: table (nslots u64) | bitmap (NBWORDS+4 u32) |
    //            cnts (2KB = 27 padded counters) | wfrag (8KB) | pairs
    const bool big = ws_size >= ((size_t)16 << 20);
    const int nslots = big ? (1 << 19) : (1 << 18);
    const unsigned mask = (unsigned)(nslots - 1);
    const int nbclear = NBWORDS + 4;               // +pad for wq+1 reads
    unsigned long long* table = (unsigned long long*)d_ws;
    unsigned* bitmap = (unsigned*)(table + nslots);
    unsigned* cnts = bitmap + nbclear;
    unsigned short* wfrag = (unsigned short*)((char*)cnts + 2048);
    uint2* pairs = (uint2*)((char*)wfrag + 8192);
    const size_t used = (size_t)nslots * 8 + (size_t)nbclear * 4 + 2048 + 8192;
    size_t cap_sz = (ws_size > used) ? (ws_size - used) / sizeof(uint2) : 0;
    if (cap_sz > (size_t)(4 << 20)) cap_sz = (size_t)(4 << 20);
    const unsigned rcap = (unsigned)(cap_sz / NREGION);

    {
        const int work = (nslots > nbclear) ? nslots : nbclear;
        int blocks = (work + 255) / 256;
        init_table_kernel<<<blocks, 256, 0, stream>>>(table, nslots, bitmap,
                                                      nbclear, cnts, weight,
                                                      wfrag);
    }
    {
        int blocks = (n + 255) / 256;
        insert_kernel<<<blocks, 256, 0, stream>>>(coords, n, table, mask,
                                                  bitmap);
    }
    {
        int blocks = (n + 511) / 512;   // 512 sites/block, 1 thread/site
        probe_pairs_kernel<<<blocks, 512, 0, stream>>>(coords, n, table, mask,
                                                       bitmap, cnts, pairs,
                                                       rcap);
    }
    {
        int waves = (n + 15) / 16;
        int blocks = (waves + 3) / 4;
        conv_center_mfma<<<blocks, 256, 0, stream>>>(feats, wfrag, bias, out, n);
    }
    {
        conv_pairs_kernel<<<26 * PB, 256, 0, stream>>>(feats, weight, pairs,
                                                       cnts, rcap, out);
    }
}